// Round 1
// 82.749 us; speedup vs baseline: 1.3381x; 1.3381x over previous
//
#include <hip/hip_runtime.h>
#include <math.h>

#define SH_C0 0.28209479177387814f
#define SH_C1 0.4886025119029199f
#define NEARP 0.01f
#define FARP 1e10f
#define LOWPASS 0.3f
#define ALPHA_MIN (1.0f/255.0f)
#define ALPHA_MAX 0.999f
#define MAXN 1024

// Intra-wave LDS producer->consumer fence: waits all outstanding LDS ops of
// this wave, and pins the scheduler so no LDS read is hoisted above it.
#define WAVE_LDS_FENCE() do { \
    asm volatile("s_waitcnt lgkmcnt(0)" ::: "memory"); \
    __builtin_amdgcn_sched_barrier(0); \
} while (0)

// Single fused kernel: every block preprocesses all N gaussians into LDS
// (redundantly, ~1us), then each wave bins its 8x8 tile, depth-sorts its own
// tile list in LDS (global sort is unnecessary: composite order only matters
// within a tile), and composites. No workspace, no intermediate kernels.
__global__ void __launch_bounds__(256) gs_fused(
        const float* __restrict__ means3d,
        const float* __restrict__ quats,
        const float* __restrict__ scales,
        const float* __restrict__ opacities,
        const float* __restrict__ sh,
        const float* __restrict__ c2w,
        const float* __restrict__ Kmat,
        const int* __restrict__ wp,
        const int* __restrict__ hp,
        int N, float* __restrict__ out)
{
    // 48 + 8 + 8 + 16 = 80 KB -> 2 blocks/CU (same occupancy as before)
    __shared__ __align__(16) float srec[MAXN * 12];   // AoS records, 3x float4 each
    __shared__ unsigned short list [4][MAXN];         // per-wave binned (index order)
    __shared__ unsigned short list2[4][MAXN];         // per-wave depth-sorted
    __shared__ float depl[4][MAXN];                   // per-wave staged depths

    int t = threadIdx.x;
    int wave = t >> 6, lane = t & 63;
    int W = *wp, H = *hp;
    int tiles_x = (W + 7) >> 3, tiles_y = (H + 7) >> 3;
    int total_tiles = tiles_x * tiles_y;
    int WH = W * H;

    // ---- camera setup (uniform, scalar) ----
    float t0 = c2w[3], t1 = c2w[7], t2 = c2w[11];
    float Rw[3][3];
    Rw[0][0] = c2w[0]; Rw[0][1] = c2w[4]; Rw[0][2] = c2w[8];
    Rw[1][0] = c2w[1]; Rw[1][1] = c2w[5]; Rw[1][2] = c2w[9];
    Rw[2][0] = c2w[2]; Rw[2][1] = c2w[6]; Rw[2][2] = c2w[10];
    float tw0 = -(Rw[0][0]*t0 + Rw[0][1]*t1 + Rw[0][2]*t2);
    float tw1 = -(Rw[1][0]*t0 + Rw[1][1]*t1 + Rw[1][2]*t2);
    float tw2 = -(Rw[2][0]*t0 + Rw[2][1]*t1 + Rw[2][2]*t2);
    float fx = Kmat[0], fy = Kmat[4], cx = Kmat[2], cy = Kmat[5];

    // ---- phase 1: cooperative preprocess of all N gaussians into LDS ----
    for (int g = t; g < N; g += 256) {
        float m0 = means3d[3*g+0], m1 = means3d[3*g+1], m2 = means3d[3*g+2];
        float x = Rw[0][0]*m0 + Rw[0][1]*m1 + Rw[0][2]*m2 + tw0;
        float y = Rw[1][0]*m0 + Rw[1][1]*m1 + Rw[1][2]*m2 + tw1;
        float z = Rw[2][0]*m0 + Rw[2][1]*m1 + Rw[2][2]*m2 + tw2;

        bool valid = (z > NEARP) && (z < FARP);
        float zs = valid ? z : 1.0f;
        float mean2x = fx * x / zs + cx;
        float mean2y = fy * y / zs + cy;

        float qw = quats[4*g+0], qx = quats[4*g+1], qy = quats[4*g+2], qz = quats[4*g+3];
        float qn = rsqrtf(qw*qw + qx*qx + qy*qy + qz*qz);
        qw *= qn; qx *= qn; qy *= qn; qz *= qn;
        float Rg[3][3];
        Rg[0][0] = 1.f - 2.f*(qy*qy + qz*qz); Rg[0][1] = 2.f*(qx*qy - qw*qz); Rg[0][2] = 2.f*(qx*qz + qw*qy);
        Rg[1][0] = 2.f*(qx*qy + qw*qz); Rg[1][1] = 1.f - 2.f*(qx*qx + qz*qz); Rg[1][2] = 2.f*(qy*qz - qw*qx);
        Rg[2][0] = 2.f*(qx*qz - qw*qy); Rg[2][1] = 2.f*(qy*qz + qw*qx); Rg[2][2] = 1.f - 2.f*(qx*qx + qy*qy);

        float sx = scales[3*g+0], sy = scales[3*g+1], sz = scales[3*g+2];
        float M[3][3];
        #pragma unroll
        for (int r = 0; r < 3; ++r) { M[r][0] = Rg[r][0]*sx; M[r][1] = Rg[r][1]*sy; M[r][2] = Rg[r][2]*sz; }

        float c3[3][3];
        #pragma unroll
        for (int r = 0; r < 3; ++r)
            #pragma unroll
            for (int c = 0; c < 3; ++c)
                c3[r][c] = M[r][0]*M[c][0] + M[r][1]*M[c][1] + M[r][2]*M[c][2];

        float Tm[3][3];
        #pragma unroll
        for (int r = 0; r < 3; ++r)
            #pragma unroll
            for (int c = 0; c < 3; ++c)
                Tm[r][c] = Rw[r][0]*c3[0][c] + Rw[r][1]*c3[1][c] + Rw[r][2]*c3[2][c];
        float cc[3][3];
        #pragma unroll
        for (int r = 0; r < 3; ++r)
            #pragma unroll
            for (int c = 0; c < 3; ++c)
                cc[r][c] = Tm[r][0]*Rw[c][0] + Tm[r][1]*Rw[c][1] + Tm[r][2]*Rw[c][2];

        float j00 = fx / zs;
        float j02 = -fx * x / (zs * zs);
        float j11 = fy / zs;
        float j12 = -fy * y / (zs * zs);
        float v00 = cc[0][0]*j00 + cc[0][2]*j02;
        float v02 = cc[2][0]*j00 + cc[2][2]*j02;
        float v10 = cc[0][1]*j11 + cc[0][2]*j12;
        float v12 = cc[2][1]*j11 + cc[2][2]*j12;
        float c2d00 = j00*v00 + j02*v02;
        float c2d01 = j00*v10 + j02*v12;
        float c2d11 = j11*(cc[1][1]*j11 + cc[1][2]*j12) + j12*v12;

        float a = c2d00 + LOWPASS;
        float b = c2d01;
        float c = c2d11 + LOWPASS;
        float det = a*c - b*b;
        valid = valid && (det > 0.f);
        float dets = (det > 0.f) ? det : 1.0f;
        float inv_det = 1.0f / dets;
        float conA = c * inv_det;
        float conB = -b * inv_det;
        float conC = a * inv_det;

        // SH degree-1 color
        float d0 = m0 - t0, d1 = m1 - t1, d2 = m2 - t2;
        float nrm = sqrtf(d0*d0 + d1*d1 + d2*d2);
        float inv_n = 1.0f / fmaxf(nrm, 1e-8f);
        float dxn = d0 * inv_n, dyn = d1 * inv_n, dzn = d2 * inv_n;
        const float* shi = sh + 12*g;
        float col0 = fmaxf(SH_C0*shi[0] - SH_C1*dyn*shi[3] + SH_C1*dzn*shi[6] - SH_C1*dxn*shi[9]  + 0.5f, 0.f);
        float col1 = fmaxf(SH_C0*shi[1] - SH_C1*dyn*shi[4] + SH_C1*dzn*shi[7] - SH_C1*dxn*shi[10] + 0.5f, 0.f);
        float col2 = fmaxf(SH_C0*shi[2] - SH_C1*dyn*shi[5] + SH_C1*dzn*shi[8] - SH_C1*dxn*shi[11] + 0.5f, 0.f);

        float opa = 1.0f / (1.0f + __expf(-opacities[g]));
        float opv = valid ? opa : 0.0f;

        // conservative cull radius: outside rad, alpha < 1/255 provably
        float lmax = 0.5f*(a + c) + sqrtf(0.25f*(a - c)*(a - c) + b*b);
        float rad = 0.f;
        if (valid && opv * 255.f > 1.0f) {
            float smax = logf(255.f * opv);
            rad = sqrtf(fmaxf(2.f * smax * lmax, 0.f)) * 1.02f + 0.1f;
        }

        float* o = srec + 12*g;
        o[0]  = mean2x; o[1]  = mean2y; o[2]  = conA; o[3]  = conB;
        o[4]  = conC;   o[5]  = opv;    o[6]  = col0; o[7]  = col1;
        o[8]  = col2;   o[9]  = z;      o[10] = rad;  o[11] = 0.f;
    }
    __syncthreads();   // only block-wide barrier; waves independent below

    const float4* rec4 = (const float4*)srec;

    for (int tile = blockIdx.x * 4 + wave; tile < total_tiles; tile += gridDim.x * 4) {
        int tx = tile % tiles_x, ty = tile / tiles_x;
        float tx0 = (float)(tx << 3) + 0.5f, tx1 = (float)(tx << 3) + 7.5f;
        float ty0 = (float)(ty << 3) + 0.5f, ty1 = (float)(ty << 3) + 7.5f;

        // ---- binning: order-preserving wave compaction (index order) ----
        int count = 0;
        for (int b0 = 0; b0 < N; b0 += 64) {
            int g = b0 + lane;
            int gc = (g < N) ? g : 0;
            float4 g0 = rec4[gc*3 + 0];        // mx,my,A,B
            float4 g2 = rec4[gc*3 + 2];        // b,dep,rad,0
            float mx = g0.x, my = g0.y, rad = g2.z;
            bool hit = (g < N) && (rad > 0.f)
                    && (mx - rad <= tx1) && (mx + rad >= tx0)
                    && (my - rad <= ty1) && (my + rad >= ty0);
            unsigned long long mask = __ballot(hit);
            int pre = __popcll(mask & ((1ull << lane) - 1ull));
            if (hit) list[wave][count + pre] = (unsigned short)g;
            count += (int)__popcll(mask);
        }
        WAVE_LDS_FENCE();

        // ---- per-tile depth sort (rank sort; ties broken by index order) ----
        for (int j = lane; j < count; j += 64)
            depl[wave][j] = srec[12 * (int)list[wave][j] + 9];
        WAVE_LDS_FENCE();
        for (int j = lane; j < count; j += 64) {
            float dj = depl[wave][j];
            int rank = 0;
            for (int k = 0; k < count; ++k) {
                float dk = depl[wave][k];      // broadcast LDS read
                rank += (int)((dk < dj) || (dk == dj && k < j));
            }
            list2[wave][rank] = list[wave][j];
        }
        WAVE_LDS_FENCE();

        // ---- composite ----
        int px_i = (tx << 3) + (lane & 7);
        int py_i = (ty << 3) + (lane >> 3);
        bool live = (px_i < W) && (py_i < H);
        float px = (float)px_i + 0.5f, py = (float)py_i + 0.5f;

        float T = live ? 1.0f : 0.0f;
        float cr = 0.f, cg = 0.f, cb = 0.f, acc = 0.f, ed = 0.f;

        for (int j = 0; j < count; ++j) {
            if (((j & 15) == 0) && __all(T < 1e-6f)) break;
            int gi = list2[wave][j];
            float4 g0 = rec4[gi*3 + 0];   // mx,my,A,B  (broadcast)
            float4 g1 = rec4[gi*3 + 1];   // C,op,r,g
            float4 g2 = rec4[gi*3 + 2];   // b,dep,rad,0
            float dx = px - g0.x, dy = py - g0.y;
            float sigma = 0.5f*(g0.z*dx*dx + g1.x*dy*dy) + g0.w*dx*dy;
            float alpha = fminf(g1.y * __expf(-sigma), ALPHA_MAX);
            if (sigma >= 0.f && alpha >= ALPHA_MIN) {
                float w = alpha * T;
                cr = fmaf(w, g1.z, cr);
                cg = fmaf(w, g1.w, cg);
                cb = fmaf(w, g2.x, cb);
                acc += w;
                ed = fmaf(w, g2.y, ed);
                T *= (1.0f - alpha);
            }
        }

        if (live) {
            int p = py_i * W + px_i;
            ((float4*)out)[p] = make_float4(cr, cg, cb, ed / fmaxf(acc, 1e-10f));
            out[WH*4 + p] = acc;
        }
    }
}

extern "C" void kernel_launch(void* const* d_in, const int* in_sizes, int n_in,
                              void* d_out, int out_size, void* d_ws, size_t ws_size,
                              hipStream_t stream) {
    const float* means3d   = (const float*)d_in[0];
    const float* quats     = (const float*)d_in[1];
    const float* scales    = (const float*)d_in[2];
    const float* opacities = (const float*)d_in[3];
    const float* sh        = (const float*)d_in[4];
    const float* c2w       = (const float*)d_in[5];
    const float* K         = (const float*)d_in[6];
    const int*   wp        = (const int*)d_in[7];
    const int*   hp        = (const int*)d_in[8];

    int N = in_sizes[0] / 3;

    int WH = out_size / 5;             // 4 color channels + 1 alpha per pixel
    int nblocks = (WH + 255) / 256;    // 4 tiles (waves) per block
    gs_fused<<<nblocks, 256, 0, stream>>>(
        means3d, quats, scales, opacities, sh, c2w, K, wp, hp, N, (float*)d_out);
}